// Round 10
// baseline (468.072 us; speedup 1.0000x reference)
//
#include <hip/hip_runtime.h>

// SDPA B=2 H=16 S=2048 D=64 fp32. Two kernels.
//  prep: K,V -> fp16 in MFMA lane-order fragment layout (+ per-tile fp32 V
//        column sums Vpart); mask -> additive bias (-C2 / -1e30).
//  main: flash attention, fp16 MFMA, LDS-free K-loop (lane-ordered fragments
//        load straight to VGPRs via global_load_dwordx4; compiler emits
//        fine-grained vmcnt). Block = 4 waves sharing 64 queries, K-split
//        4-way (512 keys/wave, 16 steps); grid 1024 -> 4 blocks/CU =
//        16 waves/CU = 4 waves/SIMD for cross-wave MFMA/VALU/latency overlap.
//        __launch_bounds__(256,4) pins VGPR<=128 (R9 body compiled to exactly 128).
//        Pairwise LDS combine tree, epilogue on wave 0.
// Numerics: Q*scale*log2e folded in, fp16 QK, bias preloaded in accumulator,
// raw v_exp_f32, v_cvt_pkrtz pack, L via VALU adds. Masked query -> out =
// Vsum/2048 from fp32 Vpart (reference's uniform-softmax branch).

#define Bb 2
#define Hh 16
#define Ss 2048
#define Dd 64

typedef __attribute__((ext_vector_type(8))) _Float16 f16x8;
typedef __attribute__((ext_vector_type(2))) __fp16 fp16x2;
typedef __attribute__((ext_vector_type(4))) float f32x4;

#define C2F (4.0f * 1.44269504088896340736f)
#define SCLF (0.125f * 1.44269504088896340736f)   // folded into Q

// ---------------- prepass ----------------
// Kf frag: id=((bh*32+kt)*8+slot)*64+lane, slot=T*2+c, lane=rl|(g<<4):
//   elem j = K[bh][kt*64+T*16+rl][c*32+g*8+j]
// Vf frag: slot=G*4+n, lane=m|(g<<4):
//   elem j = V[bh][kt*64+G*32+((j>>2)&1)*16+g*4+(j&3)][n*16+m]
__global__ __launch_bounds__(256) void prep_kernel(
    const float* __restrict__ K, const float* __restrict__ V,
    const int* __restrict__ mask,
    ushort* __restrict__ Kf, ushort* __restrict__ Vf,
    float* __restrict__ mb, float* __restrict__ Vpart)
{
    __shared__ ushort tile[4096];
    __shared__ float  part[16][64];
    const int t = threadIdx.x;
    const int blk = blockIdx.x;

    if (blk < 1024) {                       // ---- K tiles (LDS-staged, coalesced) ----
        const int bh = blk >> 5, kt = blk & 31;
        const float* base = K + ((size_t)bh * Ss + kt * 64) * Dd;
        #pragma unroll
        for (int i = 0; i < 4; ++i) {
            const int p  = i * 16 + (t >> 4);
            const int c0 = (t & 15) * 4;
            const float4 f = *(const float4*)(base + (size_t)p * Dd + c0);
            const int T = p >> 4, rl = p & 15;
            const int c = c0 >> 5, g = (c0 & 31) >> 3, j0 = c0 & 7;
            union { _Float16 h[4]; uint2 d; } pk;
            pk.h[0] = (_Float16)f.x; pk.h[1] = (_Float16)f.y;
            pk.h[2] = (_Float16)f.z; pk.h[3] = (_Float16)f.w;
            *(uint2*)&tile[((T * 2 + c) * 64 + (rl | (g << 4))) * 8 + j0] = pk.d;
        }
        __syncthreads();
        uint4* dst = (uint4*)(Kf + (size_t)(bh * 32 + kt) * 4096);
        const uint4* src = (const uint4*)tile;
        dst[t] = src[t]; dst[t + 256] = src[t + 256];
    } else if (blk < 2048) {                // ---- V tiles: register transpose + Vpart ----
        const int bv = blk - 1024;
        const int bh = bv >> 5, kt = bv & 31;
        const float* base = V + ((size_t)bh * Ss + kt * 64) * Dd;
        const int kb4 = (t >> 4) * 4;       // key base 0..60
        const int d0  = (t & 15) * 4;       // d base   0..60 (consecutive t -> coalesced)
        const float4 r0 = *(const float4*)(base + (size_t)(kb4 + 0) * Dd + d0);
        const float4 r1 = *(const float4*)(base + (size_t)(kb4 + 1) * Dd + d0);
        const float4 r2 = *(const float4*)(base + (size_t)(kb4 + 2) * Dd + d0);
        const float4 r3 = *(const float4*)(base + (size_t)(kb4 + 3) * Dd + d0);
        const int G = kb4 >> 5, p5 = kb4 & 31;
        const int tt = p5 >> 4, g = (p5 >> 2) & 3;
        const int j0 = tt * 4;
        const int n = d0 >> 4, m0 = d0 & 15;
        ushort* dstb = Vf + (size_t)(bh * 32 + kt) * 4096;
        const float ra[4][4] = {{r0.x, r1.x, r2.x, r3.x}, {r0.y, r1.y, r2.y, r3.y},
                                {r0.z, r1.z, r2.z, r3.z}, {r0.w, r1.w, r2.w, r3.w}};
        float4 ps;
        #pragma unroll
        for (int dd = 0; dd < 4; ++dd) {
            union { _Float16 h[4]; uint2 d; } pk;
            pk.h[0] = (_Float16)ra[dd][0]; pk.h[1] = (_Float16)ra[dd][1];
            pk.h[2] = (_Float16)ra[dd][2]; pk.h[3] = (_Float16)ra[dd][3];
            const int lane = (m0 + dd) | (g << 4);
            *(uint2*)&dstb[((G * 4 + n) * 64 + lane) * 8 + j0] = pk.d;
            ((float*)&ps)[dd] = (ra[dd][0] + ra[dd][1]) + (ra[dd][2] + ra[dd][3]);
        }
        *(float4*)&part[t >> 4][d0] = ps;   // fp32 partial column sums (4 keys)
        __syncthreads();
        if (t < 64) {
            float acc = 0.f;
            #pragma unroll
            for (int gg = 0; gg < 16; ++gg) acc += part[gg][t];
            Vpart[(size_t)(bh * 32 + kt) * 64 + t] = acc;
        }
    } else {                                // ---- mask -> bias ----
        #pragma unroll
        for (int i = 0; i < 16; ++i) {
            const int idx = i * 256 + t;
            mb[idx] = mask[idx] ? (-C2F) : -1e30f;
        }
    }
}

// ---------------- main (LDS-free K-loop, 4-way K-split) ----------------
__global__ __launch_bounds__(256, 4) void sdpa_main(
    const float* __restrict__ Q, const ushort* __restrict__ Kf,
    const ushort* __restrict__ Vf, const float* __restrict__ mbp,
    const float* __restrict__ Vpart,
    const int* __restrict__ mask, float* __restrict__ out)
{
    __shared__ float comb[2][68 * 64];      // pairwise combine buffers (34.8 KB)

    const int t  = threadIdx.x, w = t >> 6, l = t & 63;
    const int lq = l & 15, lg = l >> 4;
    const int bh = blockIdx.x & 31;         // XCD swizzle: one bh -> one L2
    const int qb = blockIdx.x >> 5;         // 0..31
    const int b  = bh >> 4;
    const int q0 = qb * 64;
    const int key0 = w * 512;               // K-split 4-way: wave's key range

    const size_t bhS = (size_t)bh * Ss;
    const ushort* kgb = Kf + (size_t)(bh * 32) * 4096;
    const ushort* vgb = Vf + (size_t)(bh * 32) * 4096;
    const float*  mbb = mbp + b * Ss;

    // ---- Q fragments: 4 subtiles, fp16, scale*log2e folded ----
    f16x8 qh[4][2];
    #pragma unroll
    for (int s = 0; s < 4; ++s) {
        const float* qrow = Q + (bhS + q0 + s * 16 + lq) * Dd + lg * 8;
        #pragma unroll
        for (int c = 0; c < 2; ++c) {
            const float4 f0 = *(const float4*)(qrow + 32 * c);
            const float4 f1 = *(const float4*)(qrow + 32 * c + 4);
            const float qf[8] = {f0.x, f0.y, f0.z, f0.w, f1.x, f1.y, f1.z, f1.w};
            union { _Float16 h[8]; f16x8 v; } pk;
            #pragma unroll
            for (int j = 0; j < 8; ++j) pk.h[j] = (_Float16)(qf[j] * SCLF);
            qh[s][c] = pk.v;
        }
    }

    f32x4 Oacc[4][4];
    float lacc[4] = {0.f, 0.f, 0.f, 0.f};
    #pragma unroll
    for (int s = 0; s < 4; ++s)
        #pragma unroll
        for (int n = 0; n < 4; ++n) Oacc[s][n] = f32x4{0.f, 0.f, 0.f, 0.f};

    // load one 32-key step's fragments + bias STRAIGHT to VGPRs
    #define LOAD(kk, KF, VF, B0, B1) do {                                       \
        const ushort* kp_ = kgb + (size_t)(kk) * 64 + l * 8;                    \
        const ushort* vp_ = vgb + (size_t)(kk) * 64 + l * 8;                    \
        KF[0] = *(const f16x8*)(kp_);                                           \
        KF[1] = *(const f16x8*)(kp_ + 512);                                     \
        KF[2] = *(const f16x8*)(kp_ + 1024);                                    \
        KF[3] = *(const f16x8*)(kp_ + 1536);                                    \
        VF[0] = *(const f16x8*)(vp_);                                           \
        VF[1] = *(const f16x8*)(vp_ + 512);                                     \
        VF[2] = *(const f16x8*)(vp_ + 1024);                                    \
        VF[3] = *(const f16x8*)(vp_ + 1536);                                    \
        B0 = *(const float4*)(mbb + (kk) + lg * 4);                             \
        B1 = *(const float4*)(mbb + (kk) + 16 + lg * 4);                        \
    } while (0)

    // one 32-key step: QK (bias in acc) -> exp/pack -> PV, all register-fed
    #define STEP(KF, VF, B0, B1) do {                                           \
        union { uint u32[4]; f16x8 v; } p8_[4];                                 \
        _Pragma("unroll")                                                       \
        for (int T_ = 0; T_ < 2; ++T_) {                                        \
            const f16x8 k0_ = KF[T_ * 2], k1_ = KF[T_ * 2 + 1];                 \
            const float4 bi_ = (T_ == 0) ? B0 : B1;                             \
            _Pragma("unroll")                                                   \
            for (int s_ = 0; s_ < 4; ++s_) {                                    \
                f32x4 sc_ = {bi_.x, bi_.y, bi_.z, bi_.w};                       \
                sc_ = __builtin_amdgcn_mfma_f32_16x16x32_f16(k0_, qh[s_][0], sc_, 0, 0, 0); \
                sc_ = __builtin_amdgcn_mfma_f32_16x16x32_f16(k1_, qh[s_][1], sc_, 0, 0, 0); \
                const float e0_ = __builtin_amdgcn_exp2f(sc_[0]);               \
                const float e1_ = __builtin_amdgcn_exp2f(sc_[1]);               \
                const float e2_ = __builtin_amdgcn_exp2f(sc_[2]);               \
                const float e3_ = __builtin_amdgcn_exp2f(sc_[3]);               \
                lacc[s_] += (e0_ + e1_) + (e2_ + e3_);                          \
                union { fp16x2 h; uint u; } pa_, pb_;                           \
                pa_.h = __builtin_amdgcn_cvt_pkrtz(e0_, e1_);                   \
                pb_.h = __builtin_amdgcn_cvt_pkrtz(e2_, e3_);                   \
                p8_[s_].u32[T_ * 2]     = pa_.u;                                \
                p8_[s_].u32[T_ * 2 + 1] = pb_.u;                                \
            }                                                                   \
        }                                                                       \
        _Pragma("unroll")                                                       \
        for (int n_ = 0; n_ < 4; ++n_) {                                        \
            const f16x8 vf_ = VF[n_];                                           \
            _Pragma("unroll")                                                   \
            for (int s_ = 0; s_ < 4; ++s_)                                      \
                Oacc[s_][n_] = __builtin_amdgcn_mfma_f32_16x16x32_f16(p8_[s_].v, vf_, Oacc[s_][n_], 0, 0, 0); \
        }                                                                       \
    } while (0)

    // ---- register-double-buffered K-loop (16 steps), unrolled by 2 ----
    f16x8 kA[4], vA[4], kB[4], vB[4];
    float4 a0, a1, b0, b1;

    LOAD(key0, kA, vA, a0, a1);
    for (int i = 0; i < 16; i += 2) {
        const int kk = key0 + i * 32;
        LOAD(kk + 32, kB, vB, b0, b1);      // in flight while A computes
        STEP(kA, vA, a0, a1);
        if (i + 2 < 16) LOAD(kk + 64, kA, vA, a0, a1);  // in flight while B computes
        STEP(kB, vB, b0, b1);
    }
    #undef LOAD
    #undef STEP

    // ---- 4-way K-split combine: pairwise LDS tree ----
    __syncthreads();
    if (w & 1) {                            // w1 -> buf0, w3 -> buf1
        float* dst = comb[w >> 1];
        int idx = 0;
        #pragma unroll
        for (int s = 0; s < 4; ++s)
            #pragma unroll
            for (int n = 0; n < 4; ++n)
                #pragma unroll
                for (int r = 0; r < 4; ++r) dst[(idx++) * 64 + l] = Oacc[s][n][r];
        #pragma unroll
        for (int s = 0; s < 4; ++s) dst[(64 + s) * 64 + l] = lacc[s];
    }
    __syncthreads();
    if (!(w & 1)) {                         // w0 += buf0, w2 += buf1
        const float* src = comb[w >> 1];
        int idx = 0;
        #pragma unroll
        for (int s = 0; s < 4; ++s)
            #pragma unroll
            for (int n = 0; n < 4; ++n)
                #pragma unroll
                for (int r = 0; r < 4; ++r) Oacc[s][n][r] += src[(idx++) * 64 + l];
        #pragma unroll
        for (int s = 0; s < 4; ++s) lacc[s] += src[(64 + s) * 64 + l];
    }
    __syncthreads();
    if (w == 2) {                           // w2 -> buf0
        float* dst = comb[0];
        int idx = 0;
        #pragma unroll
        for (int s = 0; s < 4; ++s)
            #pragma unroll
            for (int n = 0; n < 4; ++n)
                #pragma unroll
                for (int r = 0; r < 4; ++r) dst[(idx++) * 64 + l] = Oacc[s][n][r];
        #pragma unroll
        for (int s = 0; s < 4; ++s) dst[(64 + s) * 64 + l] = lacc[s];
    }
    __syncthreads();
    if (w == 0) {                           // w0 += buf0 -> full sum; epilogue
        const float* src = comb[0];
        int idx = 0;
        #pragma unroll
        for (int s = 0; s < 4; ++s)
            #pragma unroll
            for (int n = 0; n < 4; ++n)
                #pragma unroll
                for (int r = 0; r < 4; ++r) Oacc[s][n][r] += src[(idx++) * 64 + l];
        #pragma unroll
        for (int s = 0; s < 4; ++s) lacc[s] += src[(64 + s) * 64 + l];

        // Vsum for masked-query rows (fp32 partials from prep)
        float vsum[4] = {0.f, 0.f, 0.f, 0.f};
        const float* vpb = Vpart + (size_t)(bh * 32) * 64;
        #pragma unroll 4
        for (int kt2 = 0; kt2 < 32; ++kt2) {
            #pragma unroll
            for (int n = 0; n < 4; ++n) vsum[n] += vpb[kt2 * 64 + n * 16 + lq];
        }

        const float inv2048 = 1.0f / 2048.0f;
        #pragma unroll
        for (int s = 0; s < 4; ++s) {
            float L = lacc[s];
            L += __shfl_xor(L, 16, 64);
            L += __shfl_xor(L, 32, 64);     // lane x holds L[q = x&15]
            const int4 mq4 = *(const int4*)&mask[b * Ss + q0 + s * 16 + lg * 4];
            const int mqa[4] = {mq4.x, mq4.y, mq4.z, mq4.w};
            #pragma unroll
            for (int r = 0; r < 4; ++r) {
                const float invl = 1.0f / __shfl(L, lg * 4 + r, 64);
                float* orow = out + (bhS + q0 + s * 16 + lg * 4 + r) * Dd + lq;
                #pragma unroll
                for (int n = 0; n < 4; ++n)
                    orow[16 * n] = mqa[r] ? Oacc[s][n][r] * invl : vsum[n] * inv2048;
            }
        }
    }
}

extern "C" void kernel_launch(void* const* d_in, const int* in_sizes, int n_in,
                              void* d_out, int out_size, void* d_ws, size_t ws_size,
                              hipStream_t stream) {
    const float* Q    = (const float*)d_in[0];
    const float* K    = (const float*)d_in[1];
    const float* V    = (const float*)d_in[2];
    const int*   mask = (const int*)d_in[3];
    float* out = (float*)d_out;

    ushort* Kf    = (ushort*)d_ws;                        // 8.39 MB
    ushort* Vf    = Kf + (size_t)4194304;                 // 8.39 MB
    float*  mb    = (float*)(Vf + (size_t)4194304);       // 16 KB
    float*  Vpart = mb + 4096;                            // 256 KB

    hipLaunchKernelGGL(prep_kernel, dim3(2049), dim3(256), 0, stream,
                       K, V, mask, Kf, Vf, mb, Vpart);
    hipLaunchKernelGGL(sdpa_main, dim3(1024), dim3(256), 0, stream,
                       Q, Kf, Vf, mb, Vpart, mask, out);
}

// Round 11
// 161.679 us; speedup vs baseline: 2.8951x; 2.8951x over previous
//
#include <hip/hip_runtime.h>

// SDPA B=2 H=16 S=2048 D=64 fp32. Two kernels.
//  prep: K,V -> fp16 in MFMA lane-order fragment layout (+ per-tile fp32 V
//        column sums Vpart); mask -> additive bias (-C2 / -1e30).
//  main: flash attention, fp16 MFMA, LDS-free K-loop (lane-ordered fragments
//        load straight to VGPRs). Wave = 32 queries (2x16 subtiles) so the
//        body fits the 128-reg unified budget at 4 waves/SIMD. Block = 4 waves:
//        {w0,w1} share q[0:32) / {w2,w3} share q[32:64), each pair K-split
//        2-way (1024 keys, 32 steps). Grid 1024 -> exactly 4 blocks/CU,
//        16 waves/CU, 4 waves/SIMD (TLP hides L2 latency; no manual dbuf).
//        Pairwise LDS combine (w1->w0, w3->w2), epilogue on w0/w2.
// Numerics: Q*scale*log2e folded in, fp16 QK, bias preloaded in accumulator,
// raw v_exp_f32, v_cvt_pkrtz pack, L via VALU adds. Masked query -> out =
// Vsum/2048 from fp32 Vpart (reference's uniform-softmax branch).

#define Bb 2
#define Hh 16
#define Ss 2048
#define Dd 64

typedef __attribute__((ext_vector_type(8))) _Float16 f16x8;
typedef __attribute__((ext_vector_type(2))) __fp16 fp16x2;
typedef __attribute__((ext_vector_type(4))) float f32x4;

#define C2F (4.0f * 1.44269504088896340736f)
#define SCLF (0.125f * 1.44269504088896340736f)   // folded into Q

// ---------------- prepass (unchanged, verified) ----------------
__global__ __launch_bounds__(256) void prep_kernel(
    const float* __restrict__ K, const float* __restrict__ V,
    const int* __restrict__ mask,
    ushort* __restrict__ Kf, ushort* __restrict__ Vf,
    float* __restrict__ mb, float* __restrict__ Vpart)
{
    __shared__ ushort tile[4096];
    __shared__ float  part[16][64];
    const int t = threadIdx.x;
    const int blk = blockIdx.x;

    if (blk < 1024) {                       // ---- K tiles (LDS-staged, coalesced) ----
        const int bh = blk >> 5, kt = blk & 31;
        const float* base = K + ((size_t)bh * Ss + kt * 64) * Dd;
        #pragma unroll
        for (int i = 0; i < 4; ++i) {
            const int p  = i * 16 + (t >> 4);
            const int c0 = (t & 15) * 4;
            const float4 f = *(const float4*)(base + (size_t)p * Dd + c0);
            const int T = p >> 4, rl = p & 15;
            const int c = c0 >> 5, g = (c0 & 31) >> 3, j0 = c0 & 7;
            union { _Float16 h[4]; uint2 d; } pk;
            pk.h[0] = (_Float16)f.x; pk.h[1] = (_Float16)f.y;
            pk.h[2] = (_Float16)f.z; pk.h[3] = (_Float16)f.w;
            *(uint2*)&tile[((T * 2 + c) * 64 + (rl | (g << 4))) * 8 + j0] = pk.d;
        }
        __syncthreads();
        uint4* dst = (uint4*)(Kf + (size_t)(bh * 32 + kt) * 4096);
        const uint4* src = (const uint4*)tile;
        dst[t] = src[t]; dst[t + 256] = src[t + 256];
    } else if (blk < 2048) {                // ---- V tiles: register transpose + Vpart ----
        const int bv = blk - 1024;
        const int bh = bv >> 5, kt = bv & 31;
        const float* base = V + ((size_t)bh * Ss + kt * 64) * Dd;
        const int kb4 = (t >> 4) * 4;       // key base 0..60
        const int d0  = (t & 15) * 4;       // d base   0..60
        const float4 r0 = *(const float4*)(base + (size_t)(kb4 + 0) * Dd + d0);
        const float4 r1 = *(const float4*)(base + (size_t)(kb4 + 1) * Dd + d0);
        const float4 r2 = *(const float4*)(base + (size_t)(kb4 + 2) * Dd + d0);
        const float4 r3 = *(const float4*)(base + (size_t)(kb4 + 3) * Dd + d0);
        const int G = kb4 >> 5, p5 = kb4 & 31;
        const int tt = p5 >> 4, g = (p5 >> 2) & 3;
        const int j0 = tt * 4;
        const int n = d0 >> 4, m0 = d0 & 15;
        ushort* dstb = Vf + (size_t)(bh * 32 + kt) * 4096;
        const float ra[4][4] = {{r0.x, r1.x, r2.x, r3.x}, {r0.y, r1.y, r2.y, r3.y},
                                {r0.z, r1.z, r2.z, r3.z}, {r0.w, r1.w, r2.w, r3.w}};
        float4 ps;
        #pragma unroll
        for (int dd = 0; dd < 4; ++dd) {
            union { _Float16 h[4]; uint2 d; } pk;
            pk.h[0] = (_Float16)ra[dd][0]; pk.h[1] = (_Float16)ra[dd][1];
            pk.h[2] = (_Float16)ra[dd][2]; pk.h[3] = (_Float16)ra[dd][3];
            const int lane = (m0 + dd) | (g << 4);
            *(uint2*)&dstb[((G * 4 + n) * 64 + lane) * 8 + j0] = pk.d;
            ((float*)&ps)[dd] = (ra[dd][0] + ra[dd][1]) + (ra[dd][2] + ra[dd][3]);
        }
        *(float4*)&part[t >> 4][d0] = ps;
        __syncthreads();
        if (t < 64) {
            float acc = 0.f;
            #pragma unroll
            for (int gg = 0; gg < 16; ++gg) acc += part[gg][t];
            Vpart[(size_t)(bh * 32 + kt) * 64 + t] = acc;
        }
    } else {                                // ---- mask -> bias ----
        #pragma unroll
        for (int i = 0; i < 16; ++i) {
            const int idx = i * 256 + t;
            mb[idx] = mask[idx] ? (-C2F) : -1e30f;
        }
    }
}

// ---------------- main: 32q/wave, 4 waves/SIMD, LDS-free K-loop ----------------
__global__ __launch_bounds__(256, 4) void sdpa_main(
    const float* __restrict__ Q, const ushort* __restrict__ Kf,
    const ushort* __restrict__ Vf, const float* __restrict__ mbp,
    const float* __restrict__ Vpart,
    const int* __restrict__ mask, float* __restrict__ out)
{
    __shared__ float comb[2][34 * 64];      // per-pair combine buffers (17.4 KB)

    const int t  = threadIdx.x, w = t >> 6, l = t & 63;
    const int lq = l & 15, lg = l >> 4;
    const int bh = blockIdx.x & 31;         // XCD swizzle: one bh -> one L2
    const int qb = blockIdx.x >> 5;         // 0..31
    const int b  = bh >> 4;
    const int q0 = qb * 64 + (w >> 1) * 32; // wave pair's 32-query range
    const int key0 = (w & 1) * 1024;        // K-split within the pair

    const size_t bhS = (size_t)bh * Ss;
    const ushort* kgb = Kf + (size_t)(bh * 32) * 4096;
    const ushort* vgb = Vf + (size_t)(bh * 32) * 4096;
    const float*  mbb = mbp + b * Ss;

    // ---- Q fragments: 2 subtiles, fp16, scale*log2e folded ----
    f16x8 qh[2][2];
    #pragma unroll
    for (int s = 0; s < 2; ++s) {
        const float* qrow = Q + (bhS + q0 + s * 16 + lq) * Dd + lg * 8;
        #pragma unroll
        for (int c = 0; c < 2; ++c) {
            const float4 f0 = *(const float4*)(qrow + 32 * c);
            const float4 f1 = *(const float4*)(qrow + 32 * c + 4);
            const float qf[8] = {f0.x, f0.y, f0.z, f0.w, f1.x, f1.y, f1.z, f1.w};
            union { _Float16 h[8]; f16x8 v; } pk;
            #pragma unroll
            for (int j = 0; j < 8; ++j) pk.h[j] = (_Float16)(qf[j] * SCLF);
            qh[s][c] = pk.v;
        }
    }

    f32x4 Oacc[2][4];
    float lacc[2] = {0.f, 0.f};
    #pragma unroll
    for (int s = 0; s < 2; ++s)
        #pragma unroll
        for (int n = 0; n < 4; ++n) Oacc[s][n] = f32x4{0.f, 0.f, 0.f, 0.f};

    // ---- K-loop: 32 steps of 32 keys, single-buffered (TLP hides latency) ----
    #pragma unroll 2
    for (int i = 0; i < 32; ++i) {
        const int kk = key0 + i * 32;
        const ushort* kp = kgb + (size_t)kk * 64 + l * 8;
        const ushort* vp = vgb + (size_t)kk * 64 + l * 8;
        f16x8 kfr[4], vfr[4];
        kfr[0] = *(const f16x8*)(kp);
        kfr[1] = *(const f16x8*)(kp + 512);
        kfr[2] = *(const f16x8*)(kp + 1024);
        kfr[3] = *(const f16x8*)(kp + 1536);
        vfr[0] = *(const f16x8*)(vp);
        vfr[1] = *(const f16x8*)(vp + 512);
        vfr[2] = *(const f16x8*)(vp + 1024);
        vfr[3] = *(const f16x8*)(vp + 1536);
        const float4 b0 = *(const float4*)(mbb + kk + lg * 4);
        const float4 b1 = *(const float4*)(mbb + kk + 16 + lg * 4);

        union { uint u32[4]; f16x8 v; } p8[2];
        #pragma unroll
        for (int T = 0; T < 2; ++T) {
            const f16x8 k0 = kfr[T * 2], k1 = kfr[T * 2 + 1];
            const float4 bi = (T == 0) ? b0 : b1;
            #pragma unroll
            for (int s = 0; s < 2; ++s) {
                f32x4 sc = {bi.x, bi.y, bi.z, bi.w};    // bias in accumulator
                sc = __builtin_amdgcn_mfma_f32_16x16x32_f16(k0, qh[s][0], sc, 0, 0, 0);
                sc = __builtin_amdgcn_mfma_f32_16x16x32_f16(k1, qh[s][1], sc, 0, 0, 0);
                const float e0 = __builtin_amdgcn_exp2f(sc[0]);
                const float e1 = __builtin_amdgcn_exp2f(sc[1]);
                const float e2 = __builtin_amdgcn_exp2f(sc[2]);
                const float e3 = __builtin_amdgcn_exp2f(sc[3]);
                lacc[s] += (e0 + e1) + (e2 + e3);
                union { fp16x2 h; uint u; } pa, pb;
                pa.h = __builtin_amdgcn_cvt_pkrtz(e0, e1);
                pb.h = __builtin_amdgcn_cvt_pkrtz(e2, e3);
                p8[s].u32[T * 2]     = pa.u;
                p8[s].u32[T * 2 + 1] = pb.u;
            }
        }
        #pragma unroll
        for (int n = 0; n < 4; ++n) {
            const f16x8 vf = vfr[n];
            #pragma unroll
            for (int s = 0; s < 2; ++s)
                Oacc[s][n] = __builtin_amdgcn_mfma_f32_16x16x32_f16(p8[s].v, vf, Oacc[s][n], 0, 0, 0);
        }
    }

    // ---- pairwise K-split combine (w1->w0, w3->w2) + epilogue ----
    __syncthreads();
    if (w & 1) {                            // w1 -> comb[0], w3 -> comb[1]
        float* dst = comb[w >> 1];
        int idx = 0;
        #pragma unroll
        for (int s = 0; s < 2; ++s)
            #pragma unroll
            for (int n = 0; n < 4; ++n)
                #pragma unroll
                for (int r = 0; r < 4; ++r) dst[(idx++) * 64 + l] = Oacc[s][n][r];
        #pragma unroll
        for (int s = 0; s < 2; ++s) dst[(32 + s) * 64 + l] = lacc[s];
    }
    __syncthreads();
    if (!(w & 1)) {                         // w0 += comb[0], w2 += comb[1]
        const float* src = comb[w >> 1];
        int idx = 0;
        #pragma unroll
        for (int s = 0; s < 2; ++s)
            #pragma unroll
            for (int n = 0; n < 4; ++n)
                #pragma unroll
                for (int r = 0; r < 4; ++r) Oacc[s][n][r] += src[(idx++) * 64 + l];
        #pragma unroll
        for (int s = 0; s < 2; ++s) lacc[s] += src[(32 + s) * 64 + l];

        // Vsum for masked-query rows (fp32 partials from prep)
        float vsum[4] = {0.f, 0.f, 0.f, 0.f};
        const float* vpb = Vpart + (size_t)(bh * 32) * 64;
        #pragma unroll 4
        for (int kt2 = 0; kt2 < 32; ++kt2) {
            #pragma unroll
            for (int n = 0; n < 4; ++n) vsum[n] += vpb[kt2 * 64 + n * 16 + lq];
        }

        const float inv2048 = 1.0f / 2048.0f;
        #pragma unroll
        for (int s = 0; s < 2; ++s) {
            float L = lacc[s];
            L += __shfl_xor(L, 16, 64);
            L += __shfl_xor(L, 32, 64);     // lane x holds L[q = x&15]
            const int4 mq4 = *(const int4*)&mask[b * Ss + q0 + s * 16 + lg * 4];
            const int mqa[4] = {mq4.x, mq4.y, mq4.z, mq4.w};
            #pragma unroll
            for (int r = 0; r < 4; ++r) {
                const float invl = 1.0f / __shfl(L, lg * 4 + r, 64);
                float* orow = out + (bhS + q0 + s * 16 + lg * 4 + r) * Dd + lq;
                #pragma unroll
                for (int n = 0; n < 4; ++n)
                    orow[16 * n] = mqa[r] ? Oacc[s][n][r] * invl : vsum[n] * inv2048;
            }
        }
    }
}

extern "C" void kernel_launch(void* const* d_in, const int* in_sizes, int n_in,
                              void* d_out, int out_size, void* d_ws, size_t ws_size,
                              hipStream_t stream) {
    const float* Q    = (const float*)d_in[0];
    const float* K    = (const float*)d_in[1];
    const float* V    = (const float*)d_in[2];
    const int*   mask = (const int*)d_in[3];
    float* out = (float*)d_out;

    ushort* Kf    = (ushort*)d_ws;                        // 8.39 MB
    ushort* Vf    = Kf + (size_t)4194304;                 // 8.39 MB
    float*  mb    = (float*)(Vf + (size_t)4194304);       // 16 KB
    float*  Vpart = mb + 4096;                            // 256 KB

    hipLaunchKernelGGL(prep_kernel, dim3(2049), dim3(256), 0, stream,
                       K, V, mask, Kf, Vf, mb, Vpart);
    hipLaunchKernelGGL(sdpa_main, dim3(1024), dim3(256), 0, stream,
                       Q, Kf, Vf, mb, Vpart, mask, out);
}